// Round 1
// baseline (427.337 us; speedup 1.0000x reference)
//
#include <hip/hip_runtime.h>

// 3D Haar DWT, level 1, zero-pad (exact pairwise), fp32.
// x: [B=2, C=32, D=64, H=128, W=128] -> out: [B, 8C, D/2, H/2, W/2]
// Subband order along channel: s = sz*4 + sy*2 + sx (depth, height, width high-pass bits).
// out[b][s*C+c][dz][dy][dx] = sum_{iz,iy,ix} sgn * x[b][c][2dz+iz][2dy+iy][2dx+ix] * (1/sqrt2)^3

#define B_N 2
#define C_N 32
#define D_N 64
#define H_N 128
#define W_N 128
#define DH (D_N / 2)
#define HH (H_N / 2)
#define WH (W_N / 2)

__global__ __launch_bounds__(256) void haar3d_kernel(const float* __restrict__ x,
                                                     float* __restrict__ out) {
    const float SCALE = 0.35355339059327373f;  // (1/sqrt(2))^3

    // 2 output W positions per thread -> float4 input row loads (16B/lane, coalesced)
    // tid bits: [b:1][c:5][dz:5][dy:6][wq:5]  (total 2^22 threads)
    int tid = blockIdx.x * 256 + threadIdx.x;
    int wq = tid & 31;          // W/4 chunk index (covers output dx = 2*wq, 2*wq+1)
    int dy = (tid >> 5) & 63;   // HH
    int dz = (tid >> 11) & 31;  // DH
    int c  = (tid >> 16) & 31;  // C
    int b  = (tid >> 21);       // B

    size_t in_base = ((((size_t)(b * C_N + c) * D_N + 2 * dz) * H_N + 2 * dy) * W_N + 4 * wq);
    const float4 r0 = *(const float4*)(x + in_base);                              // z0,y0
    const float4 r1 = *(const float4*)(x + in_base + W_N);                        // z0,y1
    const float4 r2 = *(const float4*)(x + in_base + (size_t)H_N * W_N);          // z1,y0
    const float4 r3 = *(const float4*)(x + in_base + (size_t)H_N * W_N + W_N);    // z1,y1

    // Width-axis lo/hi per row, two output positions j=0,1
    float L0[2], L1[2], L2[2], L3[2];
    float Hx0[2], Hx1[2], Hx2[2], Hx3[2];
    L0[0] = r0.x + r0.y; L0[1] = r0.z + r0.w; Hx0[0] = r0.x - r0.y; Hx0[1] = r0.z - r0.w;
    L1[0] = r1.x + r1.y; L1[1] = r1.z + r1.w; Hx1[0] = r1.x - r1.y; Hx1[1] = r1.z - r1.w;
    L2[0] = r2.x + r2.y; L2[1] = r2.z + r2.w; Hx2[0] = r2.x - r2.y; Hx2[1] = r2.z - r2.w;
    L3[0] = r3.x + r3.y; L3[1] = r3.z + r3.w; Hx3[0] = r3.x - r3.y; Hx3[1] = r3.z - r3.w;

    // Output base for subband 0; subbands are C*DH*HH*WH apart along channel dim
    size_t ob = ((((size_t)(b * 8) * C_N + c) * DH + dz) * HH + dy) * WH + 2 * wq;
    const size_t SSTRIDE = (size_t)C_N * DH * HH * WH;  // 4,194,304

    float2 v;

    // s = sz*4 + sy*2 + sx ; rows: 0=z0y0 1=z0y1 2=z1y0 3=z1y1
    // sy=1 negates rows 1,3 ; sz=1 negates rows 2,3

    // s=0: aaa
    v.x = (L0[0] + L1[0] + L2[0] + L3[0]) * SCALE;
    v.y = (L0[1] + L1[1] + L2[1] + L3[1]) * SCALE;
    *(float2*)(out + ob + 0 * SSTRIDE) = v;
    // s=1: aad
    v.x = (Hx0[0] + Hx1[0] + Hx2[0] + Hx3[0]) * SCALE;
    v.y = (Hx0[1] + Hx1[1] + Hx2[1] + Hx3[1]) * SCALE;
    *(float2*)(out + ob + 1 * SSTRIDE) = v;
    // s=2: ada
    v.x = (L0[0] - L1[0] + L2[0] - L3[0]) * SCALE;
    v.y = (L0[1] - L1[1] + L2[1] - L3[1]) * SCALE;
    *(float2*)(out + ob + 2 * SSTRIDE) = v;
    // s=3: add
    v.x = (Hx0[0] - Hx1[0] + Hx2[0] - Hx3[0]) * SCALE;
    v.y = (Hx0[1] - Hx1[1] + Hx2[1] - Hx3[1]) * SCALE;
    *(float2*)(out + ob + 3 * SSTRIDE) = v;
    // s=4: daa
    v.x = (L0[0] + L1[0] - L2[0] - L3[0]) * SCALE;
    v.y = (L0[1] + L1[1] - L2[1] - L3[1]) * SCALE;
    *(float2*)(out + ob + 4 * SSTRIDE) = v;
    // s=5: dad
    v.x = (Hx0[0] + Hx1[0] - Hx2[0] - Hx3[0]) * SCALE;
    v.y = (Hx0[1] + Hx1[1] - Hx2[1] - Hx3[1]) * SCALE;
    *(float2*)(out + ob + 5 * SSTRIDE) = v;
    // s=6: dda
    v.x = (L0[0] - L1[0] - L2[0] + L3[0]) * SCALE;
    v.y = (L0[1] - L1[1] - L2[1] + L3[1]) * SCALE;
    *(float2*)(out + ob + 6 * SSTRIDE) = v;
    // s=7: ddd
    v.x = (Hx0[0] - Hx1[0] - Hx2[0] + Hx3[0]) * SCALE;
    v.y = (Hx0[1] - Hx1[1] - Hx2[1] + Hx3[1]) * SCALE;
    *(float2*)(out + ob + 7 * SSTRIDE) = v;
}

extern "C" void kernel_launch(void* const* d_in, const int* in_sizes, int n_in,
                              void* d_out, int out_size, void* d_ws, size_t ws_size,
                              hipStream_t stream) {
    const float* x = (const float*)d_in[0];
    float* out = (float*)d_out;
    // total threads = B*C*DH*HH*(WH/2) = 2*32*32*64*32 = 2^22
    const int n_threads = B_N * C_N * DH * HH * (WH / 2);
    const int block = 256;
    const int grid = n_threads / block;  // 16384
    haar3d_kernel<<<grid, block, 0, stream>>>(x, out);
}